// Round 3
// baseline (4152.901 us; speedup 1.0000x reference)
//
#include <hip/hip_runtime.h>

#define DEV_INLINE __device__ __forceinline__

DEV_INLINE void fma4(float4& a, float s, const float4& w) {
  a.x = fmaf(s, w.x, a.x);
  a.y = fmaf(s, w.y, a.y);
  a.z = fmaf(s, w.z, a.z);
  a.w = fmaf(s, w.w, a.w);
}

DEV_INLINE float4 xform4(const float4& v, const float4& sc, const float4& sh) {
  float4 r;
  r.x = fmaxf(fmaf(v.x, sc.x, sh.x), 0.f);
  r.y = fmaxf(fmaf(v.y, sc.y, sh.y), 0.f);
  r.z = fmaxf(fmaf(v.z, sc.z, sh.z), 0.f);
  r.w = fmaxf(fmaf(v.w, sc.w, sh.w), 0.f);
  return r;
}

// HW float atomic (global_atomic_add_f32), not a CAS loop. All targets are in
// d_ws (coarse-grained), so this is legal; summation order nondeterministic,
// same as any atomic scatter (fp32 tolerance absorbs it).
DEV_INLINE void atomAdd(float* p, float v) { unsafeAtomicAdd(p, v); }

// ------------------------------------------- agg init: agg = xform?(h) (self term)
// XF: apply per-column scale/shift + relu (folded BN) while copying.
template <int C4, bool XF>
__global__ void init_agg_kernel(const float* __restrict__ in, float* __restrict__ out,
                                const float* __restrict__ ss, int n4) {
  int i = blockIdx.x * blockDim.x + threadIdx.x;
  int st = gridDim.x * blockDim.x;
  const float4* in4 = reinterpret_cast<const float4*>(in);
  float4* out4 = reinterpret_cast<float4*>(out);
  for (; i < n4; i += st) {
    float4 v = in4[i];
    if (XF) {
      int c4 = i % C4;  // pow2 template constant -> and
      float4 sc = *reinterpret_cast<const float4*>(ss + c4 * 4);
      float4 sh = *reinterpret_cast<const float4*>(ss + C4 * 4 + c4 * 4);
      v = xform4(v, sc, sh);
    }
    out4[i] = v;
  }
}

// ------------------------------------- edge scatter: agg[dst] += xform?(h[src])
template <int CH4, bool XF>  // CH4 = H/4 (16 for H=64, 32 for H=128)
__global__ void edge_scatter_kernel(const float* __restrict__ h, const int* __restrict__ src,
                                    const int* __restrict__ dst, float* __restrict__ agg,
                                    const float* __restrict__ ss, int E) {
  const int H = CH4 * 4;
  long long total = (long long)E * CH4;
  long long i = (long long)blockIdx.x * blockDim.x + threadIdx.x;
  long long st = (long long)gridDim.x * blockDim.x;
  for (; i < total; i += st) {
    int e = (int)(i / CH4);           // pow2 template constant -> shift
    int c = ((int)(i % CH4)) * 4;
    int s = src[e], d = dst[e];
    float4 v = *reinterpret_cast<const float4*>(h + (long long)s * H + c);
    if (XF) {
      float4 sc = *reinterpret_cast<const float4*>(ss + c);
      float4 sh = *reinterpret_cast<const float4*>(ss + H + c);
      v = xform4(v, sc, sh);
    }
    float* p = agg + (long long)d * H + c;
    atomAdd(p + 0, v.x);
    atomAdd(p + 1, v.y);
    atomAdd(p + 2, v.z);
    atomAdd(p + 3, v.w);
  }
}

// ------------------------------------------------- main GEMM: out = act(A@W + b)
// BM=64 rows x BN=128 cols per 256-thread block; K chunked by 64 via LDS.
// STATS: accumulates per-column sum / sum-of-squares of the (post-activation)
// output into stats[0..NC) and stats[NC..2NC) — feeds BN without a re-read pass.
template <int K, int NC, bool RELU, bool STATS>
__global__ __launch_bounds__(256) void gemm_kernel(const float* __restrict__ A,
                                                   const float* __restrict__ W,
                                                   const float* __restrict__ bias,
                                                   float* __restrict__ out,
                                                   float* __restrict__ stats, int N) {
  __shared__ float As[64 * 68];   // 64 rows x 64 k, padded stride 68 (float4-aligned)
  __shared__ float Ws[64 * 128];  // 64 k x 128 cols
  const int t = threadIdx.x;
  const int tx = t & 31, ty = t >> 5;
  const int row0 = blockIdx.x * 64;
  const int col0 = blockIdx.y * 128;

  float4 acc[8];
#pragma unroll
  for (int i = 0; i < 8; ++i) acc[i] = make_float4(0.f, 0.f, 0.f, 0.f);

  for (int kc = 0; kc < K; kc += 64) {
    __syncthreads();
#pragma unroll
    for (int p = 0; p < 4; ++p) {  // A chunk: 64x64 floats = 1024 float4
      int s = p * 256 + t;
      int r = s >> 4, kq = (s & 15) << 2;
      float4 v = make_float4(0.f, 0.f, 0.f, 0.f);
      if (row0 + r < N)
        v = *reinterpret_cast<const float4*>(A + (long long)(row0 + r) * K + kc + kq);
      *reinterpret_cast<float4*>(As + r * 68 + kq) = v;
    }
#pragma unroll
    for (int p = 0; p < 8; ++p) {  // W chunk: 64x128 floats = 2048 float4
      int s = p * 256 + t;
      int k = s >> 5, c = (s & 31) << 2;
      *reinterpret_cast<float4*>(Ws + k * 128 + c) =
          *reinterpret_cast<const float4*>(W + (long long)(kc + k) * NC + col0 + c);
    }
    __syncthreads();
#pragma unroll
    for (int k4 = 0; k4 < 16; ++k4) {
      float4 w0 = *reinterpret_cast<const float4*>(Ws + (k4 * 4 + 0) * 128 + tx * 4);
      float4 w1 = *reinterpret_cast<const float4*>(Ws + (k4 * 4 + 1) * 128 + tx * 4);
      float4 w2 = *reinterpret_cast<const float4*>(Ws + (k4 * 4 + 2) * 128 + tx * 4);
      float4 w3 = *reinterpret_cast<const float4*>(Ws + (k4 * 4 + 3) * 128 + tx * 4);
#pragma unroll
      for (int i = 0; i < 8; ++i) {
        float4 a = *reinterpret_cast<const float4*>(As + (ty * 8 + i) * 68 + k4 * 4);
        fma4(acc[i], a.x, w0);
        fma4(acc[i], a.y, w1);
        fma4(acc[i], a.z, w2);
        fma4(acc[i], a.w, w3);
      }
    }
  }

  const float4 b4 = *reinterpret_cast<const float4*>(bias + col0 + tx * 4);
  float ps[4] = {0.f, 0.f, 0.f, 0.f}, pq[4] = {0.f, 0.f, 0.f, 0.f};
#pragma unroll
  for (int i = 0; i < 8; ++i) {
    int row = row0 + ty * 8 + i;
    float4 v = acc[i];
    v.x += b4.x; v.y += b4.y; v.z += b4.z; v.w += b4.w;
    if (RELU) {
      v.x = fmaxf(v.x, 0.f); v.y = fmaxf(v.y, 0.f);
      v.z = fmaxf(v.z, 0.f); v.w = fmaxf(v.w, 0.f);
    }
    if (row < N) {
      *reinterpret_cast<float4*>(out + (long long)row * NC + col0 + tx * 4) = v;
      if (STATS) {
        ps[0] += v.x; ps[1] += v.y; ps[2] += v.z; ps[3] += v.w;
        pq[0] += v.x * v.x; pq[1] += v.y * v.y; pq[2] += v.z * v.z; pq[3] += v.w * v.w;
      }
    }
  }
  if (STATS) {
    __syncthreads();  // As no longer read; reuse as reduction scratch
    float* r1 = As;
    float* r2 = As + 1024;
#pragma unroll
    for (int j = 0; j < 4; ++j) {
      r1[ty * 128 + tx * 4 + j] = ps[j];
      r2[ty * 128 + tx * 4 + j] = pq[j];
    }
    __syncthreads();
    if (t < 128) {
      float s = 0.f, s2 = 0.f;
#pragma unroll
      for (int q = 0; q < 8; ++q) { s += r1[q * 128 + t]; s2 += r2[q * 128 + t]; }
      atomAdd(&stats[col0 + t], s);
      atomAdd(&stats[NC + col0 + t], s2);
    }
  }
}

// ------------------------------------------------- BN finalize: fold to scale/shift
__global__ void bn_finalize_kernel(const float* __restrict__ stats, const float* __restrict__ g,
                                   const float* __restrict__ b, float* __restrict__ ss, int C,
                                   float invN) {
  int c = blockIdx.x * blockDim.x + threadIdx.x;
  if (c < C) {
    float mean = stats[c] * invN;
    float var = stats[C + c] * invN - mean * mean;
    float rstd = rsqrtf(var + 1e-5f);
    float scale = g[c] * rstd;
    ss[c] = scale;
    ss[C + c] = b[c] - mean * scale;
  }
}

// --------------------------- per-graph add-pool of xform?(h) (no atomics)
template <int C, bool XF>
__global__ void pool_kernel(const float* __restrict__ h, const int* __restrict__ batch,
                            const float* __restrict__ ss, float* __restrict__ pooled, int N,
                            int colOff) {
  constexpr int CH4 = C / 4;
  constexpr int RPG = 256 / CH4;
  const int g = blockIdx.x;
  const int t = threadIdx.x;
  // rs = lower_bound(batch, g), re = upper_bound(batch, g)  (batch sorted)
  int lo = 0, hi = N;
  while (lo < hi) { int m = (lo + hi) >> 1; if (batch[m] < g) lo = m + 1; else hi = m; }
  const int rs = lo;
  hi = N;
  while (lo < hi) { int m = (lo + hi) >> 1; if (batch[m] <= g) lo = m + 1; else hi = m; }
  const int re = lo;

  const int c = (t % CH4) * 4;
  const int rp = t / CH4;
  float4 sc, sh;
  if (XF) {
    sc = *reinterpret_cast<const float4*>(ss + c);
    sh = *reinterpret_cast<const float4*>(ss + C + c);
  }
  float4 acc = make_float4(0.f, 0.f, 0.f, 0.f);
  for (int r = rs + rp; r < re; r += RPG) {
    float4 v = *reinterpret_cast<const float4*>(h + (long long)r * C + c);
    if (XF) v = xform4(v, sc, sh);
    acc.x += v.x; acc.y += v.y; acc.z += v.z; acc.w += v.w;
  }
  __shared__ float4 red[256];
  red[t] = acc;
  __syncthreads();
  if (t < CH4) {
    float4 s = red[t];
#pragma unroll
    for (int q = 1; q < RPG; ++q) {
      float4 v = red[q * CH4 + t];
      s.x += v.x; s.y += v.y; s.z += v.z; s.w += v.w;
    }
    *reinterpret_cast<float4*>(pooled + g * 768 + colOff + t * 4) = s;
  }
}

// ------------------------------------------------- small-M readout GEMM
template <bool RELU>
__global__ __launch_bounds__(256) void small_gemm_kernel(const float* __restrict__ A,
                                                         const float* __restrict__ W,
                                                         const float* __restrict__ bias,
                                                         float* __restrict__ out, int K, int NC) {
  const int t = threadIdx.x;
  const int tx = t & 15, rl = t >> 4;
  const int row = blockIdx.x * 16 + rl;
  const int col = blockIdx.y * 64 + tx * 4;
  const float* a = A + (long long)row * K;
  const float* w = W + col;
  float4 acc = make_float4(0.f, 0.f, 0.f, 0.f);
  for (int k = 0; k < K; k += 4) {
    float4 a4 = *reinterpret_cast<const float4*>(a + k);
    float4 w0 = *reinterpret_cast<const float4*>(w + (long long)(k + 0) * NC);
    float4 w1 = *reinterpret_cast<const float4*>(w + (long long)(k + 1) * NC);
    float4 w2 = *reinterpret_cast<const float4*>(w + (long long)(k + 2) * NC);
    float4 w3 = *reinterpret_cast<const float4*>(w + (long long)(k + 3) * NC);
    fma4(acc, a4.x, w0);
    fma4(acc, a4.y, w1);
    fma4(acc, a4.z, w2);
    fma4(acc, a4.w, w3);
  }
  float4 b4 = *reinterpret_cast<const float4*>(bias + col);
  acc.x += b4.x; acc.y += b4.y; acc.z += b4.z; acc.w += b4.w;
  if (RELU) {
    acc.x = fmaxf(acc.x, 0.f); acc.y = fmaxf(acc.y, 0.f);
    acc.z = fmaxf(acc.z, 0.f); acc.w = fmaxf(acc.w, 0.f);
  }
  *reinterpret_cast<float4*>(out + (long long)row * NC + col) = acc;
}

static inline int imin_(int a, int b) { return a < b ? a : b; }
static inline int cdiv_(long long a, long long b) { return (int)((a + b - 1) / b); }

extern "C" void kernel_launch(void* const* d_in, const int* in_sizes, int n_in,
                              void* d_out, int out_size, void* d_ws, size_t ws_size,
                              hipStream_t stream) {
  const int N = in_sizes[0] / 64;
  const int E = in_sizes[1] / 2;
  const float* x = (const float*)d_in[0];
  const int* ei = (const int*)d_in[1];
  const int* batch = (const int*)d_in[2];
  const float *w1a = (const float*)d_in[3], *b1a = (const float*)d_in[4];
  const float *w1b = (const float*)d_in[5], *b1b = (const float*)d_in[6];
  const float *g1 = (const float*)d_in[7], *bt1 = (const float*)d_in[8];
  const float *w2a = (const float*)d_in[9], *b2a = (const float*)d_in[10];
  const float *w2b = (const float*)d_in[11], *b2b = (const float*)d_in[12];
  const float *g2 = (const float*)d_in[13], *bt2 = (const float*)d_in[14];
  const float *w3 = (const float*)d_in[15], *b3 = (const float*)d_in[16];
  const float *g3 = (const float*)d_in[17], *bt3 = (const float*)d_in[18];
  const float *wl1 = (const float*)d_in[19], *bl1 = (const float*)d_in[20];
  const float *wl2 = (const float*)d_in[21], *bl2 = (const float*)d_in[22];
  const int* src = ei;
  const int* dst = ei + E;

  float* ws = (float*)d_ws;
  float* buf0 = ws;                            // N*128
  float* buf1 = buf0 + (size_t)N * 128;        // N*128
  float* buf2 = buf1 + (size_t)N * 128;        // N*128 (raw pre-BN layer outputs)
  float* buf3 = buf2 + (size_t)N * 128;        // N*512 (raw z3 = relu(agg@w3+b3))
  float* pooled = buf3 + (size_t)N * 512;      // 256*768
  float* l1 = pooled + 256 * 768;              // 256*1024
  float* sums = l1 + 256 * 1024;               // 1536: [s1(256) s2(256) s3(1024)]
  float* ssb = sums + 1536;                    // 1536: folded BN scale/shift

  hipMemsetAsync(sums, 0, 1536 * sizeof(float), stream);

  const int NB = (N + 63) / 64;
  const float invN = 1.0f / (float)N;
  float* ss1 = ssb;         // 128 scale + 128 shift
  float* ss2 = ssb + 256;   // 128 + 128
  float* ss3 = ssb + 512;   // 512 + 512

  // ---------- layer 1: z1 = relu(agg(x)@w1a+b1a)@w1b+b1b  (raw, pre-BN)
  init_agg_kernel<16, false><<<imin_(cdiv_((long long)N * 16, 256), 8192), 256, 0, stream>>>(
      x, buf0, nullptr, N * 16);
  edge_scatter_kernel<16, false><<<imin_(cdiv_((long long)E * 16, 256), 65536), 256, 0, stream>>>(
      x, src, dst, buf0, nullptr, E);
  gemm_kernel<64, 128, true, false><<<dim3(NB, 1), 256, 0, stream>>>(buf0, w1a, b1a, buf1, nullptr, N);
  gemm_kernel<128, 128, false, true><<<dim3(NB, 1), 256, 0, stream>>>(buf1, w1b, b1b, buf2, sums, N);
  bn_finalize_kernel<<<1, 128, 0, stream>>>(sums, g1, bt1, ss1, 128, invN);
  // h1 = relu(bn1(z1)) is never materialized: ss1 is folded into pool/init/scatter.
  pool_kernel<128, true><<<256, 256, 0, stream>>>(buf2, batch, ss1, pooled, N, 0);

  // ---------- layer 2: z2 (raw) from agg(h1); h1 applied on the fly from buf2+ss1
  init_agg_kernel<32, true><<<imin_(cdiv_((long long)N * 32, 256), 8192), 256, 0, stream>>>(
      buf2, buf1, ss1, N * 32);
  edge_scatter_kernel<32, true><<<imin_(cdiv_((long long)E * 32, 256), 65536), 256, 0, stream>>>(
      buf2, src, dst, buf1, ss1, E);
  gemm_kernel<128, 128, true, false><<<dim3(NB, 1), 256, 0, stream>>>(buf1, w2a, b2a, buf0, nullptr, N);
  gemm_kernel<128, 128, false, true><<<dim3(NB, 1), 256, 0, stream>>>(buf0, w2b, b2b, buf2, sums + 256, N);
  bn_finalize_kernel<<<1, 128, 0, stream>>>(sums + 256, g2, bt2, ss2, 128, invN);
  pool_kernel<128, true><<<256, 256, 0, stream>>>(buf2, batch, ss2, pooled, N, 128);

  // ---------- layer 3: z3 = relu(agg(h2)@w3+b3); h2 applied on the fly from buf2+ss2
  init_agg_kernel<32, true><<<imin_(cdiv_((long long)N * 32, 256), 8192), 256, 0, stream>>>(
      buf2, buf1, ss2, N * 32);
  edge_scatter_kernel<32, true><<<imin_(cdiv_((long long)E * 32, 256), 65536), 256, 0, stream>>>(
      buf2, src, dst, buf1, ss2, E);
  gemm_kernel<128, 512, true, true><<<dim3(NB, 4), 256, 0, stream>>>(buf1, w3, b3, buf3, sums + 512, N);
  bn_finalize_kernel<<<1, 512, 0, stream>>>(sums + 512, g3, bt3, ss3, 512, invN);
  pool_kernel<512, true><<<256, 256, 0, stream>>>(buf3, batch, ss3, pooled, N, 256);

  // ---------- readout: out = relu(pooled@wl1+bl1)@wl2+bl2
  small_gemm_kernel<true><<<dim3(16, 16), 256, 0, stream>>>(pooled, wl1, bl1, l1, 768, 1024);
  small_gemm_kernel<false><<<dim3(16, 4), 256, 0, stream>>>(l1, wl2, bl2, (float*)d_out, 1024, 256);
}

// Round 4
// 1128.581 us; speedup vs baseline: 3.6798x; 3.6798x over previous
//
#include <hip/hip_runtime.h>

#define DEV_INLINE __device__ __forceinline__

DEV_INLINE void fma4(float4& a, float s, const float4& w) {
  a.x = fmaf(s, w.x, a.x);
  a.y = fmaf(s, w.y, a.y);
  a.z = fmaf(s, w.z, a.z);
  a.w = fmaf(s, w.w, a.w);
}

DEV_INLINE float4 xform4(const float4& v, const float4& sc, const float4& sh) {
  float4 r;
  r.x = fmaxf(fmaf(v.x, sc.x, sh.x), 0.f);
  r.y = fmaxf(fmaf(v.y, sc.y, sh.y), 0.f);
  r.z = fmaxf(fmaf(v.z, sc.z, sh.z), 0.f);
  r.w = fmaxf(fmaf(v.w, sc.w, sh.w), 0.f);
  return r;
}

// HW float atomic for the tiny BN-stats reduction (targets in d_ws).
DEV_INLINE void atomAddF(float* p, float v) { unsafeAtomicAdd(p, v); }

// ======================= CSR build (once per launch; ~4 MB scratch) ==========
// deg histogram of dst
__global__ void hist_kernel(const int* __restrict__ dst, int* __restrict__ deg, int E) {
  int i = blockIdx.x * blockDim.x + threadIdx.x;
  int st = gridDim.x * blockDim.x;
  for (; i < E; i += st) atomicAdd(&deg[dst[i]], 1);
}

// single-block exclusive scan: deg[N] -> rowStart[N+1], cursor[N]
__global__ __launch_bounds__(1024) void scan_kernel(const int* __restrict__ deg,
                                                    int* __restrict__ rowStart,
                                                    int* __restrict__ cursor, int N) {
  __shared__ int part[1024];
  const int t = threadIdx.x;
  const int chunk = (N + 1023) / 1024;
  const int base = t * chunk;
  int s = 0;
  for (int i = 0; i < chunk; ++i) {
    int idx = base + i;
    if (idx < N) s += deg[idx];
  }
  part[t] = s;
  __syncthreads();
  for (int off = 1; off < 1024; off <<= 1) {
    int u = (t >= off) ? part[t - off] : 0;
    __syncthreads();
    part[t] += u;
    __syncthreads();
  }
  int running = part[t] - s;  // exclusive offset for this thread's chunk
  for (int i = 0; i < chunk; ++i) {
    int idx = base + i;
    if (idx < N) {
      rowStart[idx] = running;
      cursor[idx] = running;
      running += deg[idx];
    }
  }
  if (t == 1023) rowStart[N] = part[1023];
}

// fill adjacency: adj[slot] = src, slot from per-dst cursor
__global__ void fill_kernel(const int* __restrict__ src, const int* __restrict__ dst,
                            int* __restrict__ cursor, int* __restrict__ adj, int E) {
  int i = blockIdx.x * blockDim.x + threadIdx.x;
  int st = gridDim.x * blockDim.x;
  for (; i < E; i += st) {
    int slot = atomicAdd(&cursor[dst[i]], 1);
    adj[slot] = src[i];
  }
}

// ================= GIN aggregation via CSR gather (atomic-free) ==============
// agg[n] = xform?(h[n]) + sum_{e in in(n)} xform?(h[adj[e]])
// Thread layout: CH4 consecutive threads own the float4 chunks of one node ->
// each gather iteration is a coalesced 512B (H=128) / 256B (H=64) row read.
template <int CH4, bool XF>  // CH4 = H/4
__global__ __launch_bounds__(256) void gather_kernel(const float* __restrict__ h,
                                                     const int* __restrict__ rowStart,
                                                     const int* __restrict__ adj,
                                                     const float* __restrict__ ss,
                                                     float* __restrict__ agg, int N) {
  constexpr int H = CH4 * 4;
  constexpr int NPB = 256 / CH4;
  const int t = threadIdx.x;
  const int c4 = t % CH4;  // pow2 -> and
  const int nl = t / CH4;  // pow2 -> shift
  const int node = blockIdx.x * NPB + nl;
  if (node >= N) return;
  const int c = c4 * 4;
  float4 sc, sh;
  if (XF) {
    sc = *reinterpret_cast<const float4*>(ss + c);
    sh = *reinterpret_cast<const float4*>(ss + H + c);
  }
  float4 acc = *reinterpret_cast<const float4*>(h + (long long)node * H + c);
  if (XF) acc = xform4(acc, sc, sh);
  const int e1 = rowStart[node + 1];
  for (int i = rowStart[node]; i < e1; ++i) {
    int s = adj[i];  // same addr across the CH4 group -> broadcast
    float4 u = *reinterpret_cast<const float4*>(h + (long long)s * H + c);
    if (XF) u = xform4(u, sc, sh);
    acc.x += u.x; acc.y += u.y; acc.z += u.z; acc.w += u.w;
  }
  *reinterpret_cast<float4*>(agg + (long long)node * H + c) = acc;
}

// ------------------------------------------------- main GEMM: out = act(A@W + b)
// BM=64 rows x BN=128 cols per 256-thread block; K chunked by 64 via LDS.
// STATS: accumulates per-column sum / sum-of-squares of the (post-activation)
// output into stats[0..NC) and stats[NC..2NC) — feeds BN without a re-read pass.
template <int K, int NC, bool RELU, bool STATS>
__global__ __launch_bounds__(256) void gemm_kernel(const float* __restrict__ A,
                                                   const float* __restrict__ W,
                                                   const float* __restrict__ bias,
                                                   float* __restrict__ out,
                                                   float* __restrict__ stats, int N) {
  __shared__ float As[64 * 68];   // 64 rows x 64 k, padded stride 68 (float4-aligned)
  __shared__ float Ws[64 * 128];  // 64 k x 128 cols
  const int t = threadIdx.x;
  const int tx = t & 31, ty = t >> 5;
  const int row0 = blockIdx.x * 64;
  const int col0 = blockIdx.y * 128;

  float4 acc[8];
#pragma unroll
  for (int i = 0; i < 8; ++i) acc[i] = make_float4(0.f, 0.f, 0.f, 0.f);

  for (int kc = 0; kc < K; kc += 64) {
    __syncthreads();
#pragma unroll
    for (int p = 0; p < 4; ++p) {  // A chunk: 64x64 floats = 1024 float4
      int s = p * 256 + t;
      int r = s >> 4, kq = (s & 15) << 2;
      float4 v = make_float4(0.f, 0.f, 0.f, 0.f);
      if (row0 + r < N)
        v = *reinterpret_cast<const float4*>(A + (long long)(row0 + r) * K + kc + kq);
      *reinterpret_cast<float4*>(As + r * 68 + kq) = v;
    }
#pragma unroll
    for (int p = 0; p < 8; ++p) {  // W chunk: 64x128 floats = 2048 float4
      int s = p * 256 + t;
      int k = s >> 5, c = (s & 31) << 2;
      *reinterpret_cast<float4*>(Ws + k * 128 + c) =
          *reinterpret_cast<const float4*>(W + (long long)(kc + k) * NC + col0 + c);
    }
    __syncthreads();
#pragma unroll
    for (int k4 = 0; k4 < 16; ++k4) {
      float4 w0 = *reinterpret_cast<const float4*>(Ws + (k4 * 4 + 0) * 128 + tx * 4);
      float4 w1 = *reinterpret_cast<const float4*>(Ws + (k4 * 4 + 1) * 128 + tx * 4);
      float4 w2 = *reinterpret_cast<const float4*>(Ws + (k4 * 4 + 2) * 128 + tx * 4);
      float4 w3 = *reinterpret_cast<const float4*>(Ws + (k4 * 4 + 3) * 128 + tx * 4);
#pragma unroll
      for (int i = 0; i < 8; ++i) {
        float4 a = *reinterpret_cast<const float4*>(As + (ty * 8 + i) * 68 + k4 * 4);
        fma4(acc[i], a.x, w0);
        fma4(acc[i], a.y, w1);
        fma4(acc[i], a.z, w2);
        fma4(acc[i], a.w, w3);
      }
    }
  }

  const float4 b4 = *reinterpret_cast<const float4*>(bias + col0 + tx * 4);
  float ps[4] = {0.f, 0.f, 0.f, 0.f}, pq[4] = {0.f, 0.f, 0.f, 0.f};
#pragma unroll
  for (int i = 0; i < 8; ++i) {
    int row = row0 + ty * 8 + i;
    float4 v = acc[i];
    v.x += b4.x; v.y += b4.y; v.z += b4.z; v.w += b4.w;
    if (RELU) {
      v.x = fmaxf(v.x, 0.f); v.y = fmaxf(v.y, 0.f);
      v.z = fmaxf(v.z, 0.f); v.w = fmaxf(v.w, 0.f);
    }
    if (row < N) {
      *reinterpret_cast<float4*>(out + (long long)row * NC + col0 + tx * 4) = v;
      if (STATS) {
        ps[0] += v.x; ps[1] += v.y; ps[2] += v.z; ps[3] += v.w;
        pq[0] += v.x * v.x; pq[1] += v.y * v.y; pq[2] += v.z * v.z; pq[3] += v.w * v.w;
      }
    }
  }
  if (STATS) {
    __syncthreads();  // As no longer read; reuse as reduction scratch
    float* r1 = As;
    float* r2 = As + 1024;
#pragma unroll
    for (int j = 0; j < 4; ++j) {
      r1[ty * 128 + tx * 4 + j] = ps[j];
      r2[ty * 128 + tx * 4 + j] = pq[j];
    }
    __syncthreads();
    if (t < 128) {
      float s = 0.f, s2 = 0.f;
#pragma unroll
      for (int q = 0; q < 8; ++q) { s += r1[q * 128 + t]; s2 += r2[q * 128 + t]; }
      atomAddF(&stats[col0 + t], s);
      atomAddF(&stats[NC + col0 + t], s2);
    }
  }
}

// ------------------------------------------------- BN finalize: fold to scale/shift
__global__ void bn_finalize_kernel(const float* __restrict__ stats, const float* __restrict__ g,
                                   const float* __restrict__ b, float* __restrict__ ss, int C,
                                   float invN) {
  int c = blockIdx.x * blockDim.x + threadIdx.x;
  if (c < C) {
    float mean = stats[c] * invN;
    float var = stats[C + c] * invN - mean * mean;
    float rstd = rsqrtf(var + 1e-5f);
    float scale = g[c] * rstd;
    ss[c] = scale;
    ss[C + c] = b[c] - mean * scale;
  }
}

// --------------------------- per-graph add-pool of xform?(h) (no atomics)
template <int C, bool XF>
__global__ void pool_kernel(const float* __restrict__ h, const int* __restrict__ batch,
                            const float* __restrict__ ss, float* __restrict__ pooled, int N,
                            int colOff) {
  constexpr int CH4 = C / 4;
  constexpr int RPG = 256 / CH4;
  const int g = blockIdx.x;
  const int t = threadIdx.x;
  // rs = lower_bound(batch, g), re = upper_bound(batch, g)  (batch sorted)
  int lo = 0, hi = N;
  while (lo < hi) { int m = (lo + hi) >> 1; if (batch[m] < g) lo = m + 1; else hi = m; }
  const int rs = lo;
  hi = N;
  while (lo < hi) { int m = (lo + hi) >> 1; if (batch[m] <= g) lo = m + 1; else hi = m; }
  const int re = lo;

  const int c = (t % CH4) * 4;
  const int rp = t / CH4;
  float4 sc, sh;
  if (XF) {
    sc = *reinterpret_cast<const float4*>(ss + c);
    sh = *reinterpret_cast<const float4*>(ss + C + c);
  }
  float4 acc = make_float4(0.f, 0.f, 0.f, 0.f);
  for (int r = rs + rp; r < re; r += RPG) {
    float4 v = *reinterpret_cast<const float4*>(h + (long long)r * C + c);
    if (XF) v = xform4(v, sc, sh);
    acc.x += v.x; acc.y += v.y; acc.z += v.z; acc.w += v.w;
  }
  __shared__ float4 red[256];
  red[t] = acc;
  __syncthreads();
  if (t < CH4) {
    float4 s = red[t];
#pragma unroll
    for (int q = 1; q < RPG; ++q) {
      float4 v = red[q * CH4 + t];
      s.x += v.x; s.y += v.y; s.z += v.z; s.w += v.w;
    }
    *reinterpret_cast<float4*>(pooled + g * 768 + colOff + t * 4) = s;
  }
}

// ------------------------------------------------- small-M readout GEMM
template <bool RELU>
__global__ __launch_bounds__(256) void small_gemm_kernel(const float* __restrict__ A,
                                                         const float* __restrict__ W,
                                                         const float* __restrict__ bias,
                                                         float* __restrict__ out, int K, int NC) {
  const int t = threadIdx.x;
  const int tx = t & 15, rl = t >> 4;
  const int row = blockIdx.x * 16 + rl;
  const int col = blockIdx.y * 64 + tx * 4;
  const float* a = A + (long long)row * K;
  const float* w = W + col;
  float4 acc = make_float4(0.f, 0.f, 0.f, 0.f);
  for (int k = 0; k < K; k += 4) {
    float4 a4 = *reinterpret_cast<const float4*>(a + k);
    float4 w0 = *reinterpret_cast<const float4*>(w + (long long)(k + 0) * NC);
    float4 w1 = *reinterpret_cast<const float4*>(w + (long long)(k + 1) * NC);
    float4 w2 = *reinterpret_cast<const float4*>(w + (long long)(k + 2) * NC);
    float4 w3 = *reinterpret_cast<const float4*>(w + (long long)(k + 3) * NC);
    fma4(acc, a4.x, w0);
    fma4(acc, a4.y, w1);
    fma4(acc, a4.z, w2);
    fma4(acc, a4.w, w3);
  }
  float4 b4 = *reinterpret_cast<const float4*>(bias + col);
  acc.x += b4.x; acc.y += b4.y; acc.z += b4.z; acc.w += b4.w;
  if (RELU) {
    acc.x = fmaxf(acc.x, 0.f); acc.y = fmaxf(acc.y, 0.f);
    acc.z = fmaxf(acc.z, 0.f); acc.w = fmaxf(acc.w, 0.f);
  }
  *reinterpret_cast<float4*>(out + (long long)row * NC + col) = acc;
}

static inline int imin_(int a, int b) { return a < b ? a : b; }
static inline int cdiv_(long long a, long long b) { return (int)((a + b - 1) / b); }

extern "C" void kernel_launch(void* const* d_in, const int* in_sizes, int n_in,
                              void* d_out, int out_size, void* d_ws, size_t ws_size,
                              hipStream_t stream) {
  const int N = in_sizes[0] / 64;
  const int E = in_sizes[1] / 2;
  const float* x = (const float*)d_in[0];
  const int* ei = (const int*)d_in[1];
  const int* batch = (const int*)d_in[2];
  const float *w1a = (const float*)d_in[3], *b1a = (const float*)d_in[4];
  const float *w1b = (const float*)d_in[5], *b1b = (const float*)d_in[6];
  const float *g1 = (const float*)d_in[7], *bt1 = (const float*)d_in[8];
  const float *w2a = (const float*)d_in[9], *b2a = (const float*)d_in[10];
  const float *w2b = (const float*)d_in[11], *b2b = (const float*)d_in[12];
  const float *g2 = (const float*)d_in[13], *bt2 = (const float*)d_in[14];
  const float *w3 = (const float*)d_in[15], *b3 = (const float*)d_in[16];
  const float *g3 = (const float*)d_in[17], *bt3 = (const float*)d_in[18];
  const float *wl1 = (const float*)d_in[19], *bl1 = (const float*)d_in[20];
  const float *wl2 = (const float*)d_in[21], *bl2 = (const float*)d_in[22];
  const int* src = ei;
  const int* dst = ei + E;

  float* ws = (float*)d_ws;
  float* buf0 = ws;                            // N*128
  float* buf1 = buf0 + (size_t)N * 128;        // N*128
  float* buf2 = buf1 + (size_t)N * 128;        // N*128 (raw pre-BN layer outputs)
  float* buf3 = buf2 + (size_t)N * 128;        // N*512 (raw z3; CSR overlaid pre-write)
  float* pooled = buf3 + (size_t)N * 512;      // 256*768
  float* l1 = pooled + 256 * 768;              // 256*1024
  float* sums = l1 + 256 * 1024;               // 1536: [s1(256) s2(256) s3(1024)]
  float* ssb = sums + 1536;                    // 1536: folded BN scale/shift

  // CSR scratch overlaid on buf3: dead before the layer-3 GEMM writes buf3.
  int* rowStart = (int*)buf3;                  // N+1
  int* cursor = rowStart + (N + 1);            // N
  int* adj = cursor + N;                       // E
  int* deg = adj + E;                          // N

  hipMemsetAsync(sums, 0, 1536 * sizeof(float), stream);
  hipMemsetAsync(deg, 0, (size_t)N * sizeof(int), stream);

  const int NB = (N + 63) / 64;
  const float invN = 1.0f / (float)N;
  float* ss1 = ssb;         // 128 scale + 128 shift
  float* ss2 = ssb + 256;   // 128 + 128
  float* ss3 = ssb + 512;   // 512 + 512

  // ---------- CSR build (shared by all 3 layers)
  hist_kernel<<<imin_(cdiv_(E, 256), 8192), 256, 0, stream>>>(dst, deg, E);
  scan_kernel<<<1, 1024, 0, stream>>>(deg, rowStart, cursor, N);
  fill_kernel<<<imin_(cdiv_(E, 256), 8192), 256, 0, stream>>>(src, dst, cursor, adj, E);

  // ---------- layer 1: z1 = relu(agg(x)@w1a+b1a)@w1b+b1b  (raw, pre-BN)
  gather_kernel<16, false><<<cdiv_(N, 16), 256, 0, stream>>>(x, rowStart, adj, nullptr, buf0, N);
  gemm_kernel<64, 128, true, false><<<dim3(NB, 1), 256, 0, stream>>>(buf0, w1a, b1a, buf1, nullptr, N);
  gemm_kernel<128, 128, false, true><<<dim3(NB, 1), 256, 0, stream>>>(buf1, w1b, b1b, buf2, sums, N);
  bn_finalize_kernel<<<1, 128, 0, stream>>>(sums, g1, bt1, ss1, 128, invN);
  // h1 = relu(bn1(z1)) never materialized: ss1 folded into pool/gather consumers.
  pool_kernel<128, true><<<256, 256, 0, stream>>>(buf2, batch, ss1, pooled, N, 0);

  // ---------- layer 2: z2 (raw) from agg(h1); h1 applied on the fly from buf2+ss1
  gather_kernel<32, true><<<cdiv_(N, 8), 256, 0, stream>>>(buf2, rowStart, adj, ss1, buf1, N);
  gemm_kernel<128, 128, true, false><<<dim3(NB, 1), 256, 0, stream>>>(buf1, w2a, b2a, buf0, nullptr, N);
  gemm_kernel<128, 128, false, true><<<dim3(NB, 1), 256, 0, stream>>>(buf0, w2b, b2b, buf2, sums + 256, N);
  bn_finalize_kernel<<<1, 128, 0, stream>>>(sums + 256, g2, bt2, ss2, 128, invN);
  pool_kernel<128, true><<<256, 256, 0, stream>>>(buf2, batch, ss2, pooled, N, 128);

  // ---------- layer 3: z3 = relu(agg(h2)@w3+b3); h2 applied on the fly from buf2+ss2
  gather_kernel<32, true><<<cdiv_(N, 8), 256, 0, stream>>>(buf2, rowStart, adj, ss2, buf1, N);
  // (CSR arrays dead from here; the next GEMM overwrites buf3.)
  gemm_kernel<128, 512, true, true><<<dim3(NB, 4), 256, 0, stream>>>(buf1, w3, b3, buf3, sums + 512, N);
  bn_finalize_kernel<<<1, 512, 0, stream>>>(sums + 512, g3, bt3, ss3, 512, invN);
  pool_kernel<512, true><<<256, 256, 0, stream>>>(buf3, batch, ss3, pooled, N, 256);

  // ---------- readout: out = relu(pooled@wl1+bl1)@wl2+bl2
  small_gemm_kernel<true><<<dim3(16, 16), 256, 0, stream>>>(pooled, wl1, bl1, l1, 768, 1024);
  small_gemm_kernel<false><<<dim3(16, 4), 256, 0, stream>>>(l1, wl2, bl2, (float*)d_out, 1024, 256);
}